// Round 7
// baseline (535.825 us; speedup 1.0000x reference)
//
#include <hip/hip_runtime.h>
#include <math.h>

#define BB 512
#define TT 1024
#define NS 50
#define SEQ 16
#define LN2F 0.6931471805599453f

typedef _Float16 f16x8 __attribute__((ext_vector_type(8)));
typedef _Float16 half2_t __attribute__((ext_vector_type(2)));
typedef float f32x4 __attribute__((ext_vector_type(4)));

#define MFMA16(A, B, C) __builtin_amdgcn_mfma_f32_16x16x32_f16((A), (B), (C), 0, 0, 0)

static __device__ __forceinline__ int pack2(float a, float b) {
    auto r = __builtin_amdgcn_cvt_pkrtz(a, b);   // a -> lo half, b -> hi half
    return __builtin_bit_cast(int, r);
}

// e-staging LDS geometry (in floats). Per slot: tiles 0-2 full (264 each = 66
// lane-slots * 4 regs) + tile3 compressed (132: 66 lane-slots * 2) = 924.
// 8 slots per direction, two directions.
#define SLOT_F 924
#define TILE_F 264
#define T3_F   792
#define DIR_F  (8 * SLOT_F)

struct ES { f32x4 a, b, c; float x0, x1; };   // per-step e in fragment order
struct LS { f32x4 a, b, c, d; };              // raw feat regs for one slot

// ============================================================================
// Kernel 1: gold path score -> ws[b]  (independent of forward/backward pass)
// ============================================================================
__global__ __launch_bounds__(128, 1) void crf_score_kernel(
    const float* __restrict__ feat,
    const float* __restrict__ trans,
    const int*   __restrict__ tags,
    const int*   __restrict__ mask,
    float* __restrict__ ws)
{
    const int b    = blockIdx.x;
    const int tid  = threadIdx.x;
    const int w    = tid >> 6;
    const int lane = tid & 63;
    __shared__ float sh_sc[2];

    int cnt = 0;
    for (int t = lane; t < TT; t += 64) cnt += mask[b * TT + t];
    #pragma unroll
    for (int k = 32; k >= 1; k >>= 1) cnt += __shfl_xor(cnt, k, 64);
    const int len = cnt;

    const float* fbb = feat + (size_t)b * TT * NS;
    const int*   tb  = tags + (size_t)b * TT;
    float sc = 0.f;
    for (int t2 = tid; t2 < len; t2 += 128) {
        int tg = tb[t2];
        sc += fbb[(size_t)t2 * NS + tg];
        if (t2 >= 1) sc += trans[tb[t2 - 1] * NS + tg];
    }
    #pragma unroll
    for (int k = 32; k >= 1; k >>= 1) sc += __shfl_xor(sc, k, 64);
    if (lane == 0) sh_sc[w] = sc;
    __syncthreads();
    if (tid == 0)
        ws[b] = sh_sc[0] + sh_sc[1] + trans[tb[0]] + trans[tb[len - 1] * NS + 1];
}

// ============================================================================
// Kernel 2: batched MFMA forward/backward.
// Block = 16 sequences, 4 waves: wv0 fwd-main, wv1 bwd-main, wv2 fwd-producer,
// wv3 bwd-producer. Slot->state convention R(g,q,e) = 16*(q>>1)+4g+2*(q&1)+e
// is applied identically to the A(E) staging and the D->B repack, so the
// contraction is correct independent of the HW k-slot mapping (it cancels).
// ============================================================================
__global__ __launch_bounds__(256, 1) void crf_main_kernel(
    const float* __restrict__ feat,
    const float* __restrict__ trans,
    const int*   __restrict__ mask,
    const float* __restrict__ score_ws,
    float* __restrict__ out)
{
    const int tid  = threadIdx.x;
    const int wv   = tid >> 6;
    const int role = wv >> 1;        // 0 = main, 1 = producer
    const int dir  = wv & 1;         // 0 = fwd, 1 = bwd
    const int l    = tid & 63;
    const int c    = l & 15;         // column = sequence slot
    const int g    = l >> 4;         // lane group
    const int base = blockIdx.x * SEQ;

    __shared__ float eL[2 * DIR_F];      // 59.1 KB
    __shared__ float comb[64][16];       // 4 KB
    __shared__ int   shK[16];

    const float* fb = feat + (size_t)(base + c) * TT * NS;   // this lane's column

    // ---- per-column length (cooperative count: 4 lanes per column) ----
    int cnt = 0;
    {
        const int4* mp4 = (const int4*)(mask + (size_t)(base + c) * TT) + g * 64;
        #pragma unroll 4
        for (int i = 0; i < 64; ++i) { int4 m = mp4[i]; cnt += m.x + m.y + m.z + m.w; }
    }
    cnt += __shfl_xor(cnt, 16, 64);
    cnt += __shfl_xor(cnt, 32, 64);
    const int len   = cnt;
    const int tm    = (len - 1) >> 1;
    const int nst   = dir ? (len - 1 - tm) : tm;
    const int lastk = nst - 1;

    int bm = (tm > len - 1 - tm) ? tm : (len - 1 - tm);
    #pragma unroll
    for (int k = 1; k < 64; k <<= 1) { int o = __shfl_xor(bm, k, 64); bm = o > bm ? o : bm; }
    const int ngroups = (bm + 3) >> 2;

    const int addr7b = (16 + c) << 2;    // bpermute: pull from lane 16+c (state 7)

    if (role == 1) {
        // ======================= PRODUCER =======================
        float* eW = eL + dir * DIR_F;
        // zero tile3 regions once (consumer reads lanes>=16 there; must be finite)
        for (int s = 0; s < 8; ++s)
            for (int o = l; o < SLOT_F - T3_F; o += 64)
                eW[s * SLOT_F + T3_F + o] = 0.f;

        auto t_of = [&](int s) { int t = dir ? (len - 2 - s) : (1 + s); return t < 0 ? 0 : t; };
        auto issue = [&](int s, LS& L) {
            const float* rp = fb + (size_t)t_of(s) * NS + 16 * g;
            if (g < 3) {
                L.a = *(const f32x4*)(rp);
                L.b = *(const f32x4*)(rp + 4);
                L.c = *(const f32x4*)(rp + 8);
                L.d = *(const f32x4*)(rp + 12);
            } else {
                float2 t2 = *(const float2*)(rp);          // states 48,49 only (bounds)
                L.a = f32x4{t2.x, t2.y, 0.f, 0.f};
            }
        };
        auto put = [&](int s, const LS& L) {
            float* wp = eW + (s & 7) * SLOT_F;
            if (g < 3) {
                f32x4 w0 = {__expf(L.a[0]), __expf(L.a[1]), __expf(L.a[2]), __expf(L.a[3])};
                f32x4 w1 = {__expf(L.b[0]), __expf(L.b[1]), __expf(L.b[2]), __expf(L.b[3])};
                f32x4 w2 = {__expf(L.c[0]), __expf(L.c[1]), __expf(L.c[2]), __expf(L.c[3])};
                f32x4 w3 = {__expf(L.d[0]), __expf(L.d[1]), __expf(L.d[2]), __expf(L.d[3])};
                float* tb_ = wp + g * TILE_F + c * 4;
                *(f32x4*)(tb_ + 0)   = w0;
                *(f32x4*)(tb_ + 64)  = w1;
                *(f32x4*)(tb_ + 128) = w2;
                *(f32x4*)(tb_ + 192) = w3;
            } else {
                float2 w = {__expf(L.a[0]), __expf(L.a[1])};
                *(float2*)(wp + T3_F + c * 2) = w;
            }
        };

        LS L0, L1, L2, L3;
        issue(0, L0); issue(1, L1); issue(2, L2); issue(3, L3);
        put(0, L0); put(1, L1); put(2, L2); put(3, L3);
        issue(4, L0); issue(5, L1); issue(6, L2); issue(7, L3);
        __syncthreads();                                   // slots 0-3 ready
        for (int gg = 0; gg < ngroups; ++gg) {
            put(4 * gg + 4, L0); put(4 * gg + 5, L1);
            put(4 * gg + 6, L2); put(4 * gg + 7, L3);
            issue(4 * gg + 8, L0);  issue(4 * gg + 9, L1);
            issue(4 * gg + 10, L2); issue(4 * gg + 11, L3);
            __syncthreads();
        }
        __syncthreads();                                   // match epilogue barrier
    } else {
        // ======================= MAIN (recurrence) =======================
        // A fragments: A[m = 16*MT + c, state k via R] ; fwd: E[k][m], bwd: E[m][k]
        f16x8 A00, A01, A10, A11, A20, A21, A30, A31;
#define MKA(VAR, MT, CH) { \
        union { int i[4]; f16x8 v; } uA; \
        _Pragma("unroll") \
        for (int q = 0; q < 4; ++q) { \
            float xv[2]; \
            _Pragma("unroll") \
            for (int ee = 0; ee < 2; ++ee) { \
                int ks = 32*(CH) + 16*(q>>1) + 4*g + 2*(q&1) + ee; \
                int mm = 16*(MT) + c; \
                float vv = 0.f; \
                if (ks < NS && mm < NS) \
                    vv = __expf(trans[dir ? (mm*NS + ks) : (ks*NS + mm)]); \
                xv[ee] = vv; \
            } \
            uA.i[q] = pack2(xv[0], xv[1]); \
        } \
        VAR = uA.v; }
        MKA(A00, 0, 0) MKA(A01, 0, 1) MKA(A10, 1, 0) MKA(A11, 1, 1)
        MKA(A20, 2, 0) MKA(A21, 2, 1) MKA(A30, 3, 0) MKA(A31, 3, 1)
#undef MKA

        // ---- init B (scaled u0), K ----
        int K = 0, snapK = 0;
        int sb0 = 0, sb1 = 0, sb2 = 0, sb3 = 0, sb4 = 0, sb5 = 0, sb6 = 0;
        f16x8 B0, B1;
        {
            float uv[2][4][2]; float ref = 1.f;
            #pragma unroll
            for (int ch = 0; ch < 2; ++ch)
            #pragma unroll
            for (int q = 0; q < 4; ++q)
            #pragma unroll
            for (int ee = 0; ee < 2; ++ee) {
                int st = 32 * ch + 16 * (q >> 1) + 4 * g + 2 * (q & 1) + ee;
                float vv = 0.f;
                if (st < NS) {
                    float tr = dir ? trans[st * NS + 1] : trans[st];
                    int t0 = dir ? (len - 1) : 0;
                    vv = __expf(tr + fb[(size_t)t0 * NS + st]);
                }
                uv[ch][q][ee] = vv;
                if (ch == 0 && q == 1 && ee == 1) ref = vv;   // state 7 on g==1 lanes
            }
            int bb = __builtin_amdgcn_ds_bpermute(addr7b, __float_as_int(ref));
            int kp = ((bb >> 23) & 255) - 127;
            K = kp;
            float rrf = __int_as_float((127 - kp) << 23);
            union { int i[4]; f16x8 v; } u0, u1;
            #pragma unroll
            for (int q = 0; q < 4; ++q) {
                u0.i[q] = pack2(uv[0][q][0] * rrf, uv[0][q][1] * rrf);
                u1.i[q] = pack2(uv[1][q][0] * rrf, uv[1][q][1] * rrf);
            }
            B0 = u0.v; B1 = u1.v;
        }

        const float* eR = eL + dir * DIR_F;
        auto RD = [&](int slot) -> ES {
            ES e;
            const float* sp = eR + slot * SLOT_F;
            e.a = *(const f32x4*)(sp + l * 4);
            e.b = *(const f32x4*)(sp + TILE_F + l * 4);
            e.c = *(const f32x4*)(sp + 2 * TILE_F + l * 4);
            float2 t2 = *(const float2*)(sp + T3_F + l * 2);
            e.x0 = t2.x; e.x1 = t2.y;
            return e;
        };
        auto STEP = [&](int k, ES e) {
            f32x4 z = {0.f, 0.f, 0.f, 0.f};
            f32x4 D0 = MFMA16(A00, B0, z); D0 = MFMA16(A01, B1, D0);
            f32x4 D1 = MFMA16(A10, B0, z); D1 = MFMA16(A11, B1, D1);
            f32x4 D2 = MFMA16(A20, B0, z); D2 = MFMA16(A21, B1, D2);
            f32x4 D3 = MFMA16(A30, B0, z); D3 = MFMA16(A31, B1, D3);
            float t00 = D0[0]*e.a[0], t01 = D0[1]*e.a[1], t02 = D0[2]*e.a[2], t03 = D0[3]*e.a[3];
            float t10 = D1[0]*e.b[0], t11 = D1[1]*e.b[1], t12 = D1[2]*e.b[2], t13 = D1[3]*e.b[3];
            float t20 = D2[0]*e.c[0], t21 = D2[1]*e.c[1], t22 = D2[2]*e.c[2], t23 = D2[3]*e.c[3];
            float t30 = D3[0]*e.x0,  t31 = D3[1]*e.x1;
            int bb = __builtin_amdgcn_ds_bpermute(addr7b, __float_as_int(t03)); // U'[7]
            int kp = ((bb >> 23) & 255) - 127;
            K += kp;
            float rrf = __int_as_float((127 - kp) << 23);
            int q0 = pack2(t00*rrf, t01*rrf), q1 = pack2(t02*rrf, t03*rrf);
            int q2 = pack2(t10*rrf, t11*rrf), q3 = pack2(t12*rrf, t13*rrf);
            int q4 = pack2(t20*rrf, t21*rrf), q5 = pack2(t22*rrf, t23*rrf);
            int q6 = pack2(t30*rrf, t31*rrf);
            union { int i[4]; f16x8 v; } n0, n1;
            n0.i[0] = q0; n0.i[1] = q1; n0.i[2] = q2; n0.i[3] = q3;
            n1.i[0] = q4; n1.i[1] = q5; n1.i[2] = q6; n1.i[3] = 0;
            B0 = n0.v; B1 = n1.v;
            bool hit = (k == lastk);
            sb0 = hit ? q0 : sb0; sb1 = hit ? q1 : sb1;
            sb2 = hit ? q2 : sb2; sb3 = hit ? q3 : sb3;
            sb4 = hit ? q4 : sb4; sb5 = hit ? q5 : sb5;
            sb6 = hit ? q6 : sb6;
            snapK = hit ? K : snapK;
        };

        __syncthreads();                                   // slots 0-3 ready
        for (int gg = 0; gg < ngroups; ++gg) {
            int sbase = (gg & 1) * 4;
            ES ea = RD(sbase + 0);
            ES eb = RD(sbase + 1);
            STEP(4 * gg + 0, ea);
            ea = RD(sbase + 2);
            STEP(4 * gg + 1, eb);
            eb = RD(sbase + 3);
            STEP(4 * gg + 2, ea);
            STEP(4 * gg + 3, eb);
            __syncthreads();
        }

        // ======================= combine =======================
        if (dir == 1) {
            int sbv[8] = {sb0, sb1, sb2, sb3, sb4, sb5, sb6, 0};
            #pragma unroll
            for (int ch = 0; ch < 2; ++ch)
            #pragma unroll
            for (int q = 0; q < 4; ++q) {
                half2_t h = __builtin_bit_cast(half2_t, sbv[ch * 4 + q]);
                #pragma unroll
                for (int ee = 0; ee < 2; ++ee) {
                    int st = 32 * ch + 16 * (q >> 1) + 4 * g + 2 * (q & 1) + ee;
                    float pb = 0.f;
                    if (st < NS)
                        pb = (float)h[ee] * __expf(-fb[(size_t)tm * NS + st]);
                    comb[l][ch * 8 + q * 2 + ee] = pb;
                }
            }
            if (l < 16) shK[l] = snapK;
        }
        __syncthreads();
        if (dir == 0) {
            int sbv[8] = {sb0, sb1, sb2, sb3, sb4, sb5, sb6, 0};
            float wvs = 0.f;
            #pragma unroll
            for (int ch = 0; ch < 2; ++ch)
            #pragma unroll
            for (int q = 0; q < 4; ++q) {
                half2_t h = __builtin_bit_cast(half2_t, sbv[ch * 4 + q]);
                wvs += (float)h[0] * comb[l][ch * 8 + q * 2 + 0];
                wvs += (float)h[1] * comb[l][ch * 8 + q * 2 + 1];
            }
            wvs += __shfl_xor(wvs, 16, 64);
            wvs += __shfl_xor(wvs, 32, 64);
            if (l < 16) {
                float log_z = __logf(wvs) + (float)(snapK + shK[l]) * LN2F;
                out[base + l] = log_z - score_ws[base + l];
            }
        }
    }
}

extern "C" void kernel_launch(void* const* d_in, const int* in_sizes, int n_in,
                              void* d_out, int out_size, void* d_ws, size_t ws_size,
                              hipStream_t stream) {
    const float* feat  = (const float*)d_in[0];
    const float* trans = (const float*)d_in[1];
    const int*   tags  = (const int*)d_in[2];
    const int*   mask  = (const int*)d_in[3];
    float* out = (float*)d_out;
    float* ws  = (float*)d_ws;
    crf_score_kernel<<<dim3(BB), dim3(128), 0, stream>>>(feat, trans, tags, mask, ws);
    crf_main_kernel<<<dim3(BB / SEQ), dim3(256), 0, stream>>>(feat, trans, mask, ws, out);
}

// Round 8
// 333.679 us; speedup vs baseline: 1.6058x; 1.6058x over previous
//
#include <hip/hip_runtime.h>
#include <math.h>

#define BB 512
#define TT 1024
#define NS 50
#define SEQ 16
#define LN2F 0.6931471805599453f

typedef _Float16 f16x8 __attribute__((ext_vector_type(8)));
typedef _Float16 half2_t __attribute__((ext_vector_type(2)));
typedef float f32x4 __attribute__((ext_vector_type(4)));

#define MFMA16(A, B, C) __builtin_amdgcn_mfma_f32_16x16x32_f16((A), (B), (C), 0, 0, 0)

static __device__ __forceinline__ int pack2(float a, float b) {
    auto r = __builtin_amdgcn_cvt_pkrtz(a, b);   // a -> lo half, b -> hi half
    return __builtin_bit_cast(int, r);
}

// slot layout: [16 seqs][56 floats], state s at offset s; 50-55 zero pad.
#define SLOT_F 896
#define RING   12          // 3 groups x 4 slots per direction

struct ES { f32x4 a, b, c; float x0, x1; };

// ============================================================================
// Kernel 1: gold path score -> ws[b]
// ============================================================================
__global__ __launch_bounds__(128, 1) void crf_score_kernel(
    const float* __restrict__ feat,
    const float* __restrict__ trans,
    const int*   __restrict__ tags,
    const int*   __restrict__ mask,
    float* __restrict__ ws)
{
    const int b    = blockIdx.x;
    const int tid  = threadIdx.x;
    const int w    = tid >> 6;
    const int lane = tid & 63;
    __shared__ float sh_sc[2];

    int cnt = 0;
    for (int t = lane; t < TT; t += 64) cnt += mask[b * TT + t];
    #pragma unroll
    for (int k = 32; k >= 1; k >>= 1) cnt += __shfl_xor(cnt, k, 64);
    const int len = cnt;

    const float* fbb = feat + (size_t)b * TT * NS;
    const int*   tb  = tags + (size_t)b * TT;
    float sc = 0.f;
    for (int t2 = tid; t2 < len; t2 += 128) {
        int tg = tb[t2];
        sc += fbb[(size_t)t2 * NS + tg];
        if (t2 >= 1) sc += trans[tb[t2 - 1] * NS + tg];
    }
    #pragma unroll
    for (int k = 32; k >= 1; k >>= 1) sc += __shfl_xor(sc, k, 64);
    if (lane == 0) sh_sc[w] = sc;
    __syncthreads();
    if (tid == 0)
        ws[b] = sh_sc[0] + sh_sc[1] + trans[tb[0]] + trans[tb[len - 1] * NS + 1];
}

// ============================================================================
// Kernel 2: batched MFMA forward/backward (schedule v2).
// ============================================================================
__global__ __launch_bounds__(256, 1) void crf_main_kernel(
    const float* __restrict__ feat,
    const float* __restrict__ trans,
    const int*   __restrict__ mask,
    const float* __restrict__ score_ws,
    float* __restrict__ out)
{
    const int tid  = threadIdx.x;
    const int wv   = tid >> 6;
    const int role = wv >> 1;        // 0 = main, 1 = producer
    const int dir  = wv & 1;         // 0 = fwd, 1 = bwd
    const int l    = tid & 63;
    const int c    = l & 15;         // consumer: column = sequence slot
    const int g    = l >> 4;         // consumer: lane group
    const int row  = l >> 2;         // producer: sequence row
    const int sub  = l & 3;          // producer: 4 lanes per row
    const int base = blockIdx.x * SEQ;

    __shared__ float eL[2][RING * SLOT_F];   // 86 KB
    __shared__ float comb[64][16];
    __shared__ int   shK[16];

    const float* fb = feat + (size_t)(base + c) * TT * NS;   // consumer's column

    // ---- per-seq length (each lane counts ITS seq with 3 partner lanes) ----
    const int myseq = role ? row : c;
    const int part  = role ? sub : g;
    int cnt = 0;
    {
        const int4* mp4 = (const int4*)(mask + (size_t)(base + myseq) * TT) + part * 64;
        #pragma unroll 4
        for (int i = 0; i < 64; ++i) { int4 m = mp4[i]; cnt += m.x + m.y + m.z + m.w; }
    }
    if (role) { cnt += __shfl_xor(cnt, 1, 64);  cnt += __shfl_xor(cnt, 2, 64);  }
    else      { cnt += __shfl_xor(cnt, 16, 64); cnt += __shfl_xor(cnt, 32, 64); }
    const int len   = cnt;
    const int tm    = (len - 1) >> 1;
    const int nst   = dir ? (len - 1 - tm) : tm;
    const int lastk = nst - 1;

    int bm = (tm > len - 1 - tm) ? tm : (len - 1 - tm);
    #pragma unroll
    for (int k = 1; k < 64; k <<= 1) { int o = __shfl_xor(bm, k, 64); bm = o > bm ? o : bm; }
    const int ngroups = (bm + 3) >> 2;

    const int addr7b = (16 + c) << 2;    // bpermute: pull from lane 16+c (state 7)

    if (role == 1) {
        // ======================= PRODUCER =======================
        float* eW = &eL[dir][0];
        // zero whole region once (pads 50-55 of every row must stay 0)
        {
            float4 z4 = {0.f, 0.f, 0.f, 0.f};
            float4* zp = (float4*)eW;
            for (int o = l; o < RING * SLOT_F / 4; o += 64) zp[o] = z4;
        }
        const float* fseq = feat + (size_t)(base + row) * TT * NS;
        struct PS { f32x4 a, b, c; float2 x; };

#define ISSUE1(s, S) { \
        int t_ = dir ? (len - 2 - (s)) : (1 + (s)); t_ = t_ < 0 ? 0 : t_; \
        const float* rp = fseq + (size_t)t_ * NS + 4 * sub; \
        S.a = *(const f32x4*)(rp); \
        S.b = *(const f32x4*)(rp + 16); \
        S.c = *(const f32x4*)(rp + 32); \
        if (sub == 0) S.x = *(const float2*)(rp + 48); }

#define PUT1(s, S) { \
        float* wp = eW + ((((s) >> 2) % 3) * 4 + ((s) & 3)) * SLOT_F + row * 56 + 4 * sub; \
        f32x4 ea_ = {__expf(S.a[0]), __expf(S.a[1]), __expf(S.a[2]), __expf(S.a[3])}; \
        f32x4 eb_ = {__expf(S.b[0]), __expf(S.b[1]), __expf(S.b[2]), __expf(S.b[3])}; \
        f32x4 ec_ = {__expf(S.c[0]), __expf(S.c[1]), __expf(S.c[2]), __expf(S.c[3])}; \
        *(f32x4*)(wp)      = ea_; \
        *(f32x4*)(wp + 16) = eb_; \
        *(f32x4*)(wp + 32) = ec_; \
        if (sub == 0) { float2 ex_ = {__expf(S.x.x), __expf(S.x.y)}; \
                        *(float2*)(wp + 48) = ex_; } }

        PS A0, A1, A2, A3, B0p, B1p, B2p, B3p;
#define ISSUEG_A(gr) { ISSUE1(4*(gr)+0, A0)  ISSUE1(4*(gr)+1, A1)  ISSUE1(4*(gr)+2, A2)  ISSUE1(4*(gr)+3, A3)  }
#define ISSUEG_B(gr) { ISSUE1(4*(gr)+0, B0p) ISSUE1(4*(gr)+1, B1p) ISSUE1(4*(gr)+2, B2p) ISSUE1(4*(gr)+3, B3p) }
#define PUTG_A(gr)   { PUT1(4*(gr)+0, A0)  PUT1(4*(gr)+1, A1)  PUT1(4*(gr)+2, A2)  PUT1(4*(gr)+3, A3)  }
#define PUTG_B(gr)   { PUT1(4*(gr)+0, B0p) PUT1(4*(gr)+1, B1p) PUT1(4*(gr)+2, B2p) PUT1(4*(gr)+3, B3p) }

        // prologue: groups 0,1 staged; groups 2,3 in flight (2-group slack)
        ISSUEG_A(0) ISSUEG_B(1)
        PUTG_A(0)   PUTG_B(1)
        ISSUEG_A(2) ISSUEG_B(3)
        __syncthreads();
        for (int gg = 0; gg < ngroups; ++gg) {
            if ((gg & 1) == 0) { PUTG_A(gg + 2) ISSUEG_A(gg + 4) }
            else               { PUTG_B(gg + 2) ISSUEG_B(gg + 4) }
            __syncthreads();
        }
        __syncthreads();                                   // match combine barrier
#undef ISSUEG_A
#undef ISSUEG_B
#undef PUTG_A
#undef PUTG_B
#undef ISSUE1
#undef PUT1
    } else {
        // ======================= MAIN (recurrence) =======================
        f16x8 A00, A01, A10, A11, A20, A21, A30, A31;
#define MKA(VAR, MT, CH) { \
        union { int i[4]; f16x8 v; } uA; \
        _Pragma("unroll") \
        for (int q = 0; q < 4; ++q) { \
            float xv[2]; \
            _Pragma("unroll") \
            for (int ee = 0; ee < 2; ++ee) { \
                int ks = 32*(CH) + 16*(q>>1) + 4*g + 2*(q&1) + ee; \
                int mm = 16*(MT) + c; \
                float vv = 0.f; \
                if (ks < NS && mm < NS) \
                    vv = __expf(trans[dir ? (mm*NS + ks) : (ks*NS + mm)]); \
                xv[ee] = vv; \
            } \
            uA.i[q] = pack2(xv[0], xv[1]); \
        } \
        VAR = uA.v; }
        MKA(A00, 0, 0) MKA(A01, 0, 1) MKA(A10, 1, 0) MKA(A11, 1, 1)
        MKA(A20, 2, 0) MKA(A21, 2, 1) MKA(A30, 3, 0) MKA(A31, 3, 1)
#undef MKA

        // ---- init B (scaled u0), K ----
        int K = 0, snapK = 0;
        int sb0 = 0, sb1 = 0, sb2 = 0, sb3 = 0, sb4 = 0, sb5 = 0, sb6 = 0;
        f16x8 B0, B1;
        {
            float uv[2][4][2]; float ref = 1.f;
            #pragma unroll
            for (int ch = 0; ch < 2; ++ch)
            #pragma unroll
            for (int q = 0; q < 4; ++q)
            #pragma unroll
            for (int ee = 0; ee < 2; ++ee) {
                int st = 32 * ch + 16 * (q >> 1) + 4 * g + 2 * (q & 1) + ee;
                float vv = 0.f;
                if (st < NS) {
                    float tr = dir ? trans[st * NS + 1] : trans[st];
                    int t0 = dir ? (len - 1) : 0;
                    vv = __expf(tr + fb[(size_t)t0 * NS + st]);
                }
                uv[ch][q][ee] = vv;
                if (ch == 0 && q == 1 && ee == 1) ref = vv;   // state 7 on g==1 lanes
            }
            int bb = __builtin_amdgcn_ds_bpermute(addr7b, __float_as_int(ref));
            int kp = ((bb >> 23) & 255) - 127;
            K = kp;
            float rrf = __int_as_float((127 - kp) << 23);
            union { int i[4]; f16x8 v; } u0, u1;
            #pragma unroll
            for (int q = 0; q < 4; ++q) {
                u0.i[q] = pack2(uv[0][q][0] * rrf, uv[0][q][1] * rrf);
                u1.i[q] = pack2(uv[1][q][0] * rrf, uv[1][q][1] * rrf);
            }
            B0 = u0.v; B1 = u1.v;
        }

        const float* eR = &eL[dir][0];
        auto RD = [&](int s) -> ES {
            const float* sp = eR + (((s >> 2) % 3) * 4 + (s & 3)) * SLOT_F + c * 56;
            ES e;
            e.a = *(const f32x4*)(sp + 4 * g);
            e.b = *(const f32x4*)(sp + 4 * g + 16);
            e.c = *(const f32x4*)(sp + 4 * g + 32);
            float2 t2 = *(const float2*)(sp + 48 + (g ? 4 : 0));
            e.x0 = t2.x; e.x1 = t2.y;
            return e;
        };
        auto STEP = [&](int k, ES e) {
            f32x4 z = {0.f, 0.f, 0.f, 0.f};
            f32x4 D0 = MFMA16(A00, B0, z); D0 = MFMA16(A01, B1, D0);
            f32x4 D1 = MFMA16(A10, B0, z); D1 = MFMA16(A11, B1, D1);
            f32x4 D2 = MFMA16(A20, B0, z); D2 = MFMA16(A21, B1, D2);
            f32x4 D3 = MFMA16(A30, B0, z); D3 = MFMA16(A31, B1, D3);
            float t00 = D0[0]*e.a[0], t01 = D0[1]*e.a[1], t02 = D0[2]*e.a[2], t03 = D0[3]*e.a[3];
            float t10 = D1[0]*e.b[0], t11 = D1[1]*e.b[1], t12 = D1[2]*e.b[2], t13 = D1[3]*e.b[3];
            float t20 = D2[0]*e.c[0], t21 = D2[1]*e.c[1], t22 = D2[2]*e.c[2], t23 = D2[3]*e.c[3];
            float t30 = D3[0]*e.x0,  t31 = D3[1]*e.x1;
            int bb = __builtin_amdgcn_ds_bpermute(addr7b, __float_as_int(t03)); // U'[7]
            int kp = ((bb >> 23) & 255) - 127;
            K += kp;
            float rrf = __int_as_float((127 - kp) << 23);
            int q0 = pack2(t00*rrf, t01*rrf), q1 = pack2(t02*rrf, t03*rrf);
            int q2 = pack2(t10*rrf, t11*rrf), q3 = pack2(t12*rrf, t13*rrf);
            int q4 = pack2(t20*rrf, t21*rrf), q5 = pack2(t22*rrf, t23*rrf);
            int q6 = pack2(t30*rrf, t31*rrf);
            union { int i[4]; f16x8 v; } n0, n1;
            n0.i[0] = q0; n0.i[1] = q1; n0.i[2] = q2; n0.i[3] = q3;
            n1.i[0] = q4; n1.i[1] = q5; n1.i[2] = q6; n1.i[3] = 0;
            B0 = n0.v; B1 = n1.v;
            bool hit = (k == lastk);
            sb0 = hit ? q0 : sb0; sb1 = hit ? q1 : sb1;
            sb2 = hit ? q2 : sb2; sb3 = hit ? q3 : sb3;
            sb4 = hit ? q4 : sb4; sb5 = hit ? q5 : sb5;
            sb6 = hit ? q6 : sb6;
            snapK = hit ? K : snapK;
        };

        __syncthreads();                                   // groups 0,1 staged
        for (int gg = 0; gg < ngroups; ++gg) {
            int s0 = 4 * gg;
            ES ea = RD(s0);
            ES eb = RD(s0 + 1);
            STEP(s0, ea);
            ea = RD(s0 + 2);
            STEP(s0 + 1, eb);
            eb = RD(s0 + 3);
            STEP(s0 + 2, ea);
            STEP(s0 + 3, eb);
            __syncthreads();
        }

        // ======================= combine =======================
        if (dir == 1) {
            int sbv[8] = {sb0, sb1, sb2, sb3, sb4, sb5, sb6, 0};
            #pragma unroll
            for (int ch = 0; ch < 2; ++ch)
            #pragma unroll
            for (int q = 0; q < 4; ++q) {
                half2_t h = __builtin_bit_cast(half2_t, sbv[ch * 4 + q]);
                #pragma unroll
                for (int ee = 0; ee < 2; ++ee) {
                    int st = 32 * ch + 16 * (q >> 1) + 4 * g + 2 * (q & 1) + ee;
                    float pb = 0.f;
                    if (st < NS)
                        pb = (float)h[ee] * __expf(-fb[(size_t)tm * NS + st]);
                    comb[l][ch * 8 + q * 2 + ee] = pb;
                }
            }
            if (l < 16) shK[l] = snapK;
        }
        __syncthreads();
        if (dir == 0) {
            int sbv[8] = {sb0, sb1, sb2, sb3, sb4, sb5, sb6, 0};
            float wvs = 0.f;
            #pragma unroll
            for (int ch = 0; ch < 2; ++ch)
            #pragma unroll
            for (int q = 0; q < 4; ++q) {
                half2_t h = __builtin_bit_cast(half2_t, sbv[ch * 4 + q]);
                wvs += (float)h[0] * comb[l][ch * 8 + q * 2 + 0];
                wvs += (float)h[1] * comb[l][ch * 8 + q * 2 + 1];
            }
            wvs += __shfl_xor(wvs, 16, 64);
            wvs += __shfl_xor(wvs, 32, 64);
            if (l < 16) {
                float log_z = __logf(wvs) + (float)(snapK + shK[l]) * LN2F;
                out[base + l] = log_z - score_ws[base + l];
            }
        }
    }
}

extern "C" void kernel_launch(void* const* d_in, const int* in_sizes, int n_in,
                              void* d_out, int out_size, void* d_ws, size_t ws_size,
                              hipStream_t stream) {
    const float* feat  = (const float*)d_in[0];
    const float* trans = (const float*)d_in[1];
    const int*   tags  = (const int*)d_in[2];
    const int*   mask  = (const int*)d_in[3];
    float* out = (float*)d_out;
    float* ws  = (float*)d_ws;
    crf_score_kernel<<<dim3(BB), dim3(128), 0, stream>>>(feat, trans, tags, mask, ws);
    crf_main_kernel<<<dim3(BB / SEQ), dim3(256), 0, stream>>>(feat, trans, mask, ws, out);
}